// Round 1
// baseline (252.580 us; speedup 1.0000x reference)
//
#include <hip/hip_runtime.h>

typedef __bf16 bf16;
typedef __bf16 bf16x2 __attribute__((ext_vector_type(2)));
typedef __bf16 bf16x8 __attribute__((ext_vector_type(8)));
typedef float  f32x4  __attribute__((ext_vector_type(4)));

#define S_LEN 4096
#define NHEAD 16
#define DHEAD 64
#define HID   1024
#define QT    64
#define KVT   64

// XOR swizzle: spreads 128B-stride rows across LDS bank groups.
// Read side (rows l&15 + 16nt) and write side must use the same involution.
__device__ __forceinline__ int swz(int row, int byteoff) {
    return (row * 128 + byteoff) ^ ((((row >> 3) ^ row) & 7) << 4);
}

__global__ __launch_bounds__(256, 2)
void fattn_kernel(const float* __restrict__ Qg,
                  const float* __restrict__ Kg,
                  const float* __restrict__ Vg,
                  float* __restrict__ Og)
{
    const int qc  = blockIdx.x;       // q chunk (64 rows)
    const int h   = blockIdx.y;       // head
    const int t   = threadIdx.x;
    const int wid = t >> 6;           // wave 0..3
    const int l   = t & 63;
    const int g   = l >> 4;           // lane group 0..3
    const int lr  = l & 15;
    const int q0  = qc * QT;

    __shared__ bf16 Kl[KVT * DHEAD];      // swizzled [key][d]
    __shared__ bf16 Vtl[DHEAD * KVT];     // swizzled [d][key] (transposed)
    __shared__ bf16 Pl[4 * 16 * 64];      // per-wave swizzled [qrow][key]

    char* const Klb  = (char*)Kl;
    char* const Vtlb = (char*)Vtl;
    char* const Plb  = (char*)Pl + wid * 2048;

    // ---- Q fragments (A-operand), scaled by 1/sqrt(64)=1/8 before bf16 ----
    // A-frag (16x16x32): lane holds row=l&15, k=(l>>4)*8 + 0..7 (contiguous)
    bf16x8 qf[2];
    {
        const float* qp = Qg + (size_t)(q0 + wid * 16 + lr) * HID + h * DHEAD + g * 8;
        #pragma unroll
        for (int kt = 0; kt < 2; ++kt) {
            float4 a = *(const float4*)(qp + kt * 32);
            float4 b = *(const float4*)(qp + kt * 32 + 4);
            float tmp[8] = {a.x, a.y, a.z, a.w, b.x, b.y, b.z, b.w};
            #pragma unroll
            for (int i = 0; i < 8; ++i) qf[kt][i] = (bf16)(tmp[i] * 0.125f);
        }
    }

    f32x4 ot[4];
    #pragma unroll
    for (int nt = 0; nt < 4; ++nt) ot[nt] = (f32x4){0.f, 0.f, 0.f, 0.f};
    float mrun[4], lrun[4];
    #pragma unroll
    for (int r = 0; r < 4; ++r) { mrun[r] = -1e30f; lrun[r] = 0.f; }

    // staging assignments
    const int skey = t >> 2;          // K: key row, 16 f32 per thread
    const int sdp  = (t & 3) * 16;
    const int vkp  = t >> 3;          // V: key pair (2 keys), 8 d per thread
    const int vdp  = (t & 7) * 8;

    const float* kbase  = Kg + (size_t)skey * HID + h * DHEAD + sdp;
    const float* vbase0 = Vg + (size_t)(2 * vkp) * HID + h * DHEAD + vdp;

    for (int kv0 = 0; kv0 < S_LEN; kv0 += KVT) {
        // ---------- stage K tile (f32 -> bf16, swizzled) ----------
        const float* kp = kbase + (size_t)kv0 * HID;
        float4 k0 = ((const float4*)kp)[0];
        float4 k1 = ((const float4*)kp)[1];
        float4 k2 = ((const float4*)kp)[2];
        float4 k3 = ((const float4*)kp)[3];
        // ---------- stage V tile transposed ----------
        const float* vp0 = vbase0 + (size_t)kv0 * HID;
        const float* vp1 = vp0 + HID;
        float4 v0a = ((const float4*)vp0)[0];
        float4 v0b = ((const float4*)vp0)[1];
        float4 v1a = ((const float4*)vp1)[0];
        float4 v1b = ((const float4*)vp1)[1];

        {
            float ka[16] = {k0.x,k0.y,k0.z,k0.w, k1.x,k1.y,k1.z,k1.w,
                            k2.x,k2.y,k2.z,k2.w, k3.x,k3.y,k3.z,k3.w};
            bf16x8 kb0, kb1;
            #pragma unroll
            for (int i = 0; i < 8; ++i) { kb0[i] = (bf16)ka[i]; kb1[i] = (bf16)ka[8 + i]; }
            *(bf16x8*)(Klb + swz(skey, sdp * 2))      = kb0;
            *(bf16x8*)(Klb + swz(skey, sdp * 2 + 16)) = kb1;
        }
        {
            float va[8] = {v0a.x,v0a.y,v0a.z,v0a.w, v0b.x,v0b.y,v0b.z,v0b.w};
            float vb[8] = {v1a.x,v1a.y,v1a.z,v1a.w, v1b.x,v1b.y,v1b.z,v1b.w};
            #pragma unroll
            for (int j = 0; j < 8; ++j) {
                bf16x2 pr;
                pr[0] = (bf16)va[j];          // key 2*vkp
                pr[1] = (bf16)vb[j];          // key 2*vkp+1
                *(bf16x2*)(Vtlb + swz(vdp + j, vkp * 4)) = pr;
            }
        }
        __syncthreads();

        // ---------- QK^T: S[16 qrows][64 keys] ----------
        f32x4 sc[4];
        #pragma unroll
        for (int nt = 0; nt < 4; ++nt) {
            bf16x8 kf0 = *(const bf16x8*)(Klb + swz(lr + 16 * nt, g * 16));
            bf16x8 kf1 = *(const bf16x8*)(Klb + swz(lr + 16 * nt, 64 + g * 16));
            f32x4 acc = (f32x4){0.f, 0.f, 0.f, 0.f};
            acc = __builtin_amdgcn_mfma_f32_16x16x32_bf16(qf[0], kf0, acc, 0, 0, 0);
            acc = __builtin_amdgcn_mfma_f32_16x16x32_bf16(qf[1], kf1, acc, 0, 0, 0);
            sc[nt] = acc;
        }

        // ---------- online softmax (wave-parallel: 16-lane group per row) ----------
        #pragma unroll
        for (int r = 0; r < 4; ++r) {
            float tm = fmaxf(fmaxf(sc[0][r], sc[1][r]), fmaxf(sc[2][r], sc[3][r]));
            tm = fmaxf(tm, __shfl_xor(tm, 1));
            tm = fmaxf(tm, __shfl_xor(tm, 2));
            tm = fmaxf(tm, __shfl_xor(tm, 4));
            tm = fmaxf(tm, __shfl_xor(tm, 8));
            const float nm    = fmaxf(mrun[r], tm);
            const float alpha = __expf(mrun[r] - nm);   // first iter: exp(-1e30)=0
            mrun[r] = nm;
            float ps = 0.f;
            #pragma unroll
            for (int nt = 0; nt < 4; ++nt) {
                float p = __expf(sc[nt][r] - nm);
                sc[nt][r] = p;
                ps += p;
            }
            ps += __shfl_xor(ps, 1);
            ps += __shfl_xor(ps, 2);
            ps += __shfl_xor(ps, 4);
            ps += __shfl_xor(ps, 8);
            lrun[r] = lrun[r] * alpha + ps;
            #pragma unroll
            for (int nt = 0; nt < 4; ++nt) ot[nt][r] *= alpha;
        }

        // ---------- P -> per-wave LDS (re-layout C-frag -> A-frag) ----------
        #pragma unroll
        for (int nt = 0; nt < 4; ++nt) {
            #pragma unroll
            for (int r = 0; r < 4; ++r) {
                *(bf16*)(Plb + swz(4 * g + r, (lr + 16 * nt) * 2)) = (bf16)sc[nt][r];
            }
        }
        asm volatile("s_waitcnt lgkmcnt(0)" ::: "memory");  // wave-local write->read fence

        // ---------- PV: O += P[16x64] * V[64x64] ----------
        bf16x8 pf0 = *(const bf16x8*)(Plb + swz(lr, g * 16));
        bf16x8 pf1 = *(const bf16x8*)(Plb + swz(lr, 64 + g * 16));
        #pragma unroll
        for (int nt = 0; nt < 4; ++nt) {
            bf16x8 vf0 = *(const bf16x8*)(Vtlb + swz(lr + 16 * nt, g * 16));
            bf16x8 vf1 = *(const bf16x8*)(Vtlb + swz(lr + 16 * nt, 64 + g * 16));
            ot[nt] = __builtin_amdgcn_mfma_f32_16x16x32_bf16(pf0, vf0, ot[nt], 0, 0, 0);
            ot[nt] = __builtin_amdgcn_mfma_f32_16x16x32_bf16(pf1, vf1, ot[nt], 0, 0, 0);
        }
        __syncthreads();
    }

    // ---------- epilogue: normalize and store ----------
    #pragma unroll
    for (int r = 0; r < 4; ++r) {
        const float inv = 1.f / lrun[r];
        float* op = Og + (size_t)(q0 + wid * 16 + 4 * g + r) * HID + h * DHEAD + lr;
        #pragma unroll
        for (int nt = 0; nt < 4; ++nt) op[16 * nt] = ot[nt][r] * inv;
    }
}

extern "C" void kernel_launch(void* const* d_in, const int* in_sizes, int n_in,
                              void* d_out, int out_size, void* d_ws, size_t ws_size,
                              hipStream_t stream) {
    const float* Q = (const float*)d_in[0];
    const float* K = (const float*)d_in[1];
    const float* V = (const float*)d_in[2];
    float* O = (float*)d_out;
    dim3 grid(S_LEN / QT, NHEAD);
    fattn_kernel<<<grid, 256, 0, stream>>>(Q, K, V, O);
}

// Round 4
// 133.773 us; speedup vs baseline: 1.8881x; 1.8881x over previous
//
#include <hip/hip_runtime.h>
#include <stdint.h>

typedef __bf16 bf16;
typedef __bf16 bf16x8 __attribute__((ext_vector_type(8)));
typedef float  f32x16 __attribute__((ext_vector_type(16)));

#define S_LEN 4096
#define NHEAD 16
#define HID   1024
#define QT    128              // q rows per block: 4 waves x 32
#define KVT   64
#define NTILE (S_LEN / KVT)    // 64
#define TILEB 8192             // one K or V tile: 64x64 bf16
// Q scale: 1/sqrt(64) * log2(e)  (softmax done in base-2: exp2)
#define QSCALE (0.125f * 1.44269504088896340736f)

#define AS1 __attribute__((address_space(1)))
#define AS3 __attribute__((address_space(3)))

// base-2 exp: v_exp_f32 computes 2^x directly
#define EXP2F(x) __builtin_amdgcn_exp2f(x)

// XOR swizzle on byte offset within a [row][128B] tile: conflict-free b128 reads.
__device__ __forceinline__ int xorv(int row) { return ((row ^ (row >> 3)) & 7) << 4; }

__device__ __forceinline__ void gload16(const void* g, void* l) {
    // async global->LDS DMA, 16B/lane; LDS dst = wave-uniform base + lane*16
    __builtin_amdgcn_global_load_lds((const AS1 uint32_t*)g, (AS3 uint32_t*)l, 16, 0, 0);
}

__device__ __forceinline__ uint32_t pack_bf16(float a, float b) {
    union { bf16 h[2]; uint32_t u; } x;
    x.h[0] = (bf16)a; x.h[1] = (bf16)b;
    return x.u;
}

// ---------------- prepass: f32 K/V -> bf16, per-(head,tile), pre-swizzled ----------------
// Kb tile layout byte b: row=key=b>>7, d = ((b&127) ^ xorv(key))/2
// Vb tile layout byte b: row=d  =b>>7, key = ((b&127) ^ xorv(d))/2   (transposed)
__global__ __launch_bounds__(256)
void prepack_kernel(const float* __restrict__ Kg, const float* __restrict__ Vg,
                    char* __restrict__ Kb, char* __restrict__ Vb)
{
    const int tile = blockIdx.x, h = blockIdx.y;
    const int t = threadIdx.x;
    __shared__ float Vs[64][65];   // +1 pad: conflict-free column reads

    const int key = t >> 2, db = (t & 3) * 16;
    const float* kp = Kg + (size_t)(tile * KVT + key) * HID + h * 64 + db;
    const float* vp = Vg + (size_t)(tile * KVT + key) * HID + h * 64 + db;
    float kv[16], vv[16];
    #pragma unroll
    for (int i = 0; i < 4; ++i) {
        *(float4*)(kv + 4 * i) = *(const float4*)(kp + 4 * i);
        *(float4*)(vv + 4 * i) = *(const float4*)(vp + 4 * i);
    }
    // K out (direct)
    {
        char* kout = Kb + (size_t)(h * NTILE + tile) * TILEB;
        const int x = xorv(key);
        bf16x8 b0, b1;
        #pragma unroll
        for (int i = 0; i < 8; ++i) { b0[i] = (bf16)kv[i]; b1[i] = (bf16)kv[8 + i]; }
        *(bf16x8*)(kout + key * 128 + ((db * 2) ^ x))      = b0;
        *(bf16x8*)(kout + key * 128 + ((db * 2 + 16) ^ x)) = b1;
    }
    // V out (transpose via LDS)
    #pragma unroll
    for (int i = 0; i < 16; ++i) Vs[key][db + i] = vv[i];
    __syncthreads();
    {
        const int d = t >> 2, kb0 = (t & 3) * 16;
        float tv[16];
        #pragma unroll
        for (int i = 0; i < 16; ++i) tv[i] = Vs[kb0 + i][d];
        char* vout = Vb + (size_t)(h * NTILE + tile) * TILEB;
        const int x = xorv(d);
        bf16x8 b0, b1;
        #pragma unroll
        for (int i = 0; i < 8; ++i) { b0[i] = (bf16)tv[i]; b1[i] = (bf16)tv[8 + i]; }
        *(bf16x8*)(vout + d * 128 + ((kb0 * 2) ^ x))      = b0;
        *(bf16x8*)(vout + d * 128 + ((kb0 * 2 + 16) ^ x)) = b1;
    }
}

// ---------------- main: flash attention, 32x32 MFMA, swapped operands ----------------
__global__ __launch_bounds__(256, 2)
void fattn_kernel(const float* __restrict__ Qg,
                  const char* __restrict__ Kb,
                  const char* __restrict__ Vb,
                  float* __restrict__ Og)
{
    const int qc = blockIdx.x;         // 0..31 (128 q rows each)
    const int h  = blockIdx.y;
    const int t  = threadIdx.x;
    const int w  = t >> 6;             // wave 0..3, owns 32 q rows
    const int l  = t & 63;
    const int lq = l & 31;             // this lane's q row (within wave) AND frag row idx
    const int hi = l >> 5;             // 32-lane half

    __shared__ __attribute__((aligned(128))) char lds[32768];
    char* const Kl = lds;              // [2][8192] double-buffered K tiles
    char* const Vl = lds + 16384;      // [2][8192] double-buffered V^T tiles

    // Q fragments: B-operand of QK^T. col=q=lq, k(d) = kc*16 + hi*8 + j
    bf16x8 qf[4];
    {
        const float* qp = Qg + (size_t)(qc * QT + w * 32 + lq) * HID + h * 64 + hi * 8;
        #pragma unroll
        for (int kc = 0; kc < 4; ++kc) {
            float tmp[8];
            *(float4*)(tmp)     = *(const float4*)(qp + kc * 16);
            *(float4*)(tmp + 4) = *(const float4*)(qp + kc * 16 + 4);
            #pragma unroll
            for (int i = 0; i < 8; ++i) qf[kc][i] = (bf16)(tmp[i] * QSCALE);
        }
    }

    f32x16 ot0, ot1;                   // O^T accumulators: d=[0,32)+... col=q=lq
    #pragma unroll
    for (int i = 0; i < 16; ++i) { ot0[i] = 0.f; ot1[i] = 0.f; }
    float mrun = -1e30f, lrun = 0.f;

    const char* Khead = Kb + (size_t)h * (NTILE * TILEB);
    const char* Vhead = Vb + (size_t)h * (NTILE * TILEB);

    // stage one 8KB K tile + 8KB V tile; wave w copies bytes [w*2048, w*2048+2048)
    auto stage = [&](int tile, int buf) {
        const char* ks = Khead + (size_t)tile * TILEB + w * 2048 + l * 16;
        const char* vs = Vhead + (size_t)tile * TILEB + w * 2048 + l * 16;
        char* kd = Kl + buf * TILEB + w * 2048;
        char* vd = Vl + buf * TILEB + w * 2048;
        gload16(ks, kd); gload16(ks + 1024, kd + 1024);
        gload16(vs, vd); gload16(vs + 1024, vd + 1024);
    };

    stage(0, 0);
    for (int it = 0; it < NTILE; ++it) {
        const int cur = it & 1;
        if (it + 1 < NTILE) {
            stage(it + 1, cur ^ 1);
            asm volatile("s_waitcnt vmcnt(4)" ::: "memory");  // cur tile landed; next 4 in flight
        } else {
            asm volatile("s_waitcnt vmcnt(0)" ::: "memory");
        }
        __builtin_amdgcn_s_barrier();
        asm volatile("" ::: "memory");

        const char* Kt = Kl + cur * TILEB;
        const char* Vt = Vl + cur * TILEB;

        // ---- QK^T (swapped): sc_s = S^T, col=q=lq, row=key=s*32+(r&3)+8(r>>2)+4hi ----
        f32x16 sc0, sc1;
        #pragma unroll
        for (int i = 0; i < 16; ++i) { sc0[i] = 0.f; sc1[i] = 0.f; }
        #pragma unroll
        for (int kc = 0; kc < 4; ++kc) {
            bf16x8 kf0 = *(const bf16x8*)(Kt + lq * 128        + ((kc * 32 + 16 * hi) ^ xorv(lq)));
            bf16x8 kf1 = *(const bf16x8*)(Kt + (32 + lq) * 128 + ((kc * 32 + 16 * hi) ^ xorv(32 + lq)));
            sc0 = __builtin_amdgcn_mfma_f32_32x32x16_bf16(kf0, qf[kc], sc0, 0, 0, 0);
            sc1 = __builtin_amdgcn_mfma_f32_32x32x16_bf16(kf1, qf[kc], sc1, 0, 0, 0);
        }

        // ---- online softmax (base-2); lane holds 32 of 64 keys, partner (l^32) holds rest ----
        float tm = sc0[0];
        #pragma unroll
        for (int i = 1; i < 16; ++i) tm = fmaxf(tm, sc0[i]);
        #pragma unroll
        for (int i = 0; i < 16; ++i) tm = fmaxf(tm, sc1[i]);
        tm = fmaxf(tm, __shfl_xor(tm, 32));
        const float nm = fmaxf(mrun, tm);
        const float alpha = EXP2F(mrun - nm);
        mrun = nm;
        float ps = 0.f;
        #pragma unroll
        for (int i = 0; i < 16; ++i) { float p = EXP2F(sc0[i] - nm); sc0[i] = p; ps += p; }
        #pragma unroll
        for (int i = 0; i < 16; ++i) { float p = EXP2F(sc1[i] - nm); sc1[i] = p; ps += p; }
        ps += __shfl_xor(ps, 32);
        lrun = lrun * alpha + ps;
        #pragma unroll
        for (int i = 0; i < 16; ++i) { ot0[i] *= alpha; ot1[i] *= alpha; }

        // ---- P -> bf16 words; pk[s][m] covers within-block keys 8*(m>>1) + 2*(m&1) + 4hi + {0,1} ----
        uint32_t pk[2][8];
        #pragma unroll
        for (int m = 0; m < 8; ++m) {
            pk[0][m] = pack_bf16(sc0[2 * m], sc0[2 * m + 1]);
            pk[1][m] = pack_bf16(sc1[2 * m], sc1[2 * m + 1]);
        }

        // ---- PV (swapped): ot += V^T[d][k] * P[k][q]; chunks c of 16 keys ----
        // B-frag word w (k-pair 16c+8hi+2w+{0,1}) placement, derived:
        //   w0 = hi ? ^pk[mb+2] : pk[mb+0]   w1 = hi ? ^pk[mb+3] : pk[mb+1]
        //   w2 = hi ? pk[mb+2] : ^pk[mb+0]   w3 = hi ? pk[mb+3] : ^pk[mb+1]
        // where ^x = partner-lane (l^32) value — __shfl_xor: unambiguous semantics.
        #pragma unroll
        for (int c = 0; c < 4; ++c) {
            const int s = c >> 1;
            const int mb = (c & 1) * 4;
            uint32_t p0 = pk[s][mb + 0], p1 = pk[s][mb + 1];
            uint32_t p2 = pk[s][mb + 2], p3 = pk[s][mb + 3];
            uint32_t q0 = __shfl_xor(p0, 32), q1 = __shfl_xor(p1, 32);
            uint32_t q2 = __shfl_xor(p2, 32), q3 = __shfl_xor(p3, 32);
            union { uint32_t w4[4]; bf16x8 v; } pb;
            pb.w4[0] = hi ? q2 : p0;
            pb.w4[1] = hi ? q3 : p1;
            pb.w4[2] = hi ? p2 : q0;
            pb.w4[3] = hi ? p3 : q1;
            bf16x8 vf0 = *(const bf16x8*)(Vt + lq * 128        + ((c * 32 + 16 * hi) ^ xorv(lq)));
            bf16x8 vf1 = *(const bf16x8*)(Vt + (32 + lq) * 128 + ((c * 32 + 16 * hi) ^ xorv(32 + lq)));
            ot0 = __builtin_amdgcn_mfma_f32_32x32x16_bf16(vf0, pb.v, ot0, 0, 0, 0);
            ot1 = __builtin_amdgcn_mfma_f32_32x32x16_bf16(vf1, pb.v, ot1, 0, 0, 0);
        }

        asm volatile("s_waitcnt lgkmcnt(0)" ::: "memory");
        __builtin_amdgcn_s_barrier();   // raw barrier: do NOT drain vmcnt (prefetch in flight)
        asm volatile("" ::: "memory");
    }

    // ---- epilogue: O^T -> LDS (swizzled f32) -> coalesced global ----
    __syncthreads();                    // safe to overwrite K/V buffers
    {
        const float inv = 1.f / lrun;
        const int qloc = w * 32 + lq;
        const int x = (qloc & 7) << 4;
        #pragma unroll
        for (int r = 0; r < 16; ++r) {
            const int d0 = (r & 3) + 8 * (r >> 2) + 4 * hi;
            *(float*)(lds + ((qloc * 256 + d0 * 4) ^ x))         = ot0[r] * inv;
            *(float*)(lds + ((qloc * 256 + (32 + d0) * 4) ^ x))  = ot1[r] * inv;
        }
    }
    __syncthreads();
    {
        const int qr = t >> 1, half = t & 1;
        const int x = (qr & 7) << 4;
        float* op = Og + (size_t)(qc * QT + qr) * HID + h * 64 + half * 32;
        #pragma unroll
        for (int i = 0; i < 8; ++i) {
            float4 v = *(const float4*)(lds + ((qr * 256 + half * 128 + i * 16) ^ x));
            *(float4*)(op + i * 4) = v;
        }
    }
}

extern "C" void kernel_launch(void* const* d_in, const int* in_sizes, int n_in,
                              void* d_out, int out_size, void* d_ws, size_t ws_size,
                              hipStream_t stream) {
    const float* Q = (const float*)d_in[0];
    const float* K = (const float*)d_in[1];
    const float* V = (const float*)d_in[2];
    float* O = (float*)d_out;
    char* Kb = (char*)d_ws;                                   // 8 MB
    char* Vb = (char*)d_ws + (size_t)NHEAD * NTILE * TILEB;   // 8 MB
    dim3 pgrid(NTILE, NHEAD);
    prepack_kernel<<<pgrid, 256, 0, stream>>>(K, V, Kb, Vb);
    dim3 grid(S_LEN / QT, NHEAD);
    fattn_kernel<<<grid, 256, 0, stream>>>(Q, Kb, Vb, O);
}

// Round 5
// 122.417 us; speedup vs baseline: 2.0633x; 1.0928x over previous
//
#include <hip/hip_runtime.h>
#include <stdint.h>

typedef __bf16 bf16;
typedef __bf16 bf16x8 __attribute__((ext_vector_type(8)));
typedef float  f32x16 __attribute__((ext_vector_type(16)));

#define S_LEN 4096
#define NHEAD 16
#define HID   1024
#define NTILE 64               // KV tiles of 64 keys
#define TILEB 8192             // one K or V tile: 64x64 bf16, fragment-major
// Q scale: 1/sqrt(64) * log2(e)  (softmax in base-2)
#define QSCALE (0.125f * 1.44269504088896340736f)
#define EXP2F(x) __builtin_amdgcn_exp2f(x)
#define DEFER_THR 8.0f

__device__ __forceinline__ uint32_t pack_bf16(float a, float b) {
    union { bf16 h[2]; uint32_t u; } x;
    x.h[0] = (bf16)a; x.h[1] = (bf16)b;
    return x.u;
}

// ---------------- prepass: f32 K/V -> bf16 fragment-major per (head,tile) ----------------
// K frag i=kc*2+r, lane l: K[tile*64 + r*32 + (l&31)][kc*16 + (l>>5)*8 + 0..7]
// V frag j=c*2+r,  lane l: V^T[r*32 + (l&31)][k = c*16 + (l>>5)*8 + 0..7]
__global__ __launch_bounds__(256)
void prepack_kernel(const float* __restrict__ Kg, const float* __restrict__ Vg,
                    char* __restrict__ Kb, char* __restrict__ Vb)
{
    const int tile = blockIdx.x, h = blockIdx.y;
    const int t = threadIdx.x;
    __shared__ float Vs[64][65];

    const int key = t >> 2, dq = (t & 3) * 16;       // kc = t&3
    const float* kp = Kg + (size_t)(tile * 64 + key) * HID + h * 64 + dq;
    const float* vp = Vg + (size_t)(tile * 64 + key) * HID + h * 64 + dq;
    float kv[16], vv[16];
    #pragma unroll
    for (int i = 0; i < 4; ++i) {
        *(float4*)(kv + 4 * i) = *(const float4*)(kp + 4 * i);
        *(float4*)(vv + 4 * i) = *(const float4*)(vp + 4 * i);
    }
    // K: direct fragment-major write
    {
        char* kout = Kb + (size_t)(h * NTILE + tile) * TILEB;
        const int i = (t & 3) * 2 + (key >> 5);
        bf16x8 b0, b1;
        #pragma unroll
        for (int e = 0; e < 8; ++e) { b0[e] = (bf16)kv[e]; b1[e] = (bf16)kv[8 + e]; }
        *(bf16x8*)(kout + i * 1024 + (key & 31) * 16)        = b0;
        *(bf16x8*)(kout + i * 1024 + (32 + (key & 31)) * 16) = b1;
    }
    // V: transpose via LDS, then fragment-major write
    #pragma unroll
    for (int e = 0; e < 16; ++e) Vs[key][dq + e] = vv[e];
    __syncthreads();
    {
        const int d = t >> 2, kq = (t & 3) * 16;     // c = t&3
        float tv[16];
        #pragma unroll
        for (int e = 0; e < 16; ++e) tv[e] = Vs[kq + e][d];
        char* vout = Vb + (size_t)(h * NTILE + tile) * TILEB;
        const int j = (t & 3) * 2 + (d >> 5);
        bf16x8 b0, b1;
        #pragma unroll
        for (int e = 0; e < 8; ++e) { b0[e] = (bf16)tv[e]; b1[e] = (bf16)tv[8 + e]; }
        *(bf16x8*)(vout + j * 1024 + (d & 31) * 16)        = b0;
        *(bf16x8*)(vout + j * 1024 + (32 + (d & 31)) * 16) = b1;
    }
}

// ---------------- main: flash attention, no LDS staging, KV-split x2 ----------------
// block = 256 threads = 4 waves = 2 q-groups (32 rows each) x 2 KV-splits (2048 keys each)
__global__ __launch_bounds__(256, 3)
void fattn_kernel(const float* __restrict__ Qg,
                  const char* __restrict__ Kb,
                  const char* __restrict__ Vb,
                  float* __restrict__ Og)
{
    // XCD swizzle: 1024 blocks, 128 per XCD -> 2 heads per XCD (KV 2MB in 4MB L2)
    const int sb = (blockIdx.x & 7) * 128 + (blockIdx.x >> 3);
    const int h  = sb >> 6;            // 0..15
    const int qc = sb & 63;            // 0..63 (64 q rows each)
    const int t  = threadIdx.x;
    const int w  = t >> 6;
    const int qg = w >> 1;             // q-group 0..1
    const int ws = w & 1;              // KV split 0..1
    const int l  = t & 63;
    const int lq = l & 31;
    const int hi = l >> 5;

    // LDS: [2 qg][64 lane][34] partials + [2 qg][32 row][256B] output staging
    __shared__ __attribute__((aligned(16))) char smem[33792];
    float* const part = (float*)smem;                    // 2*64*34 floats
    char*  const obuf = smem + 17408;                    // 2*8192 bytes

    // Q fragments (B-operand): col=q=lq, k(d) = kc*16 + hi*8 + j
    bf16x8 qf[4];
    {
        const float* qp = Qg + (size_t)(qc * 64 + qg * 32 + lq) * HID + h * 64 + hi * 8;
        #pragma unroll
        for (int kc = 0; kc < 4; ++kc) {
            float tmp[8];
            *(float4*)(tmp)     = *(const float4*)(qp + kc * 16);
            *(float4*)(tmp + 4) = *(const float4*)(qp + kc * 16 + 4);
            #pragma unroll
            for (int e = 0; e < 8; ++e) qf[kc][e] = (bf16)(tmp[e] * QSCALE);
        }
    }

    f32x16 ot0, ot1;
    #pragma unroll
    for (int i = 0; i < 16; ++i) { ot0[i] = 0.f; ot1[i] = 0.f; }
    float mrun = -1e30f, lrun = 0.f;

    const char* Khead = Kb + (size_t)h * (NTILE * TILEB) + (size_t)ws * 32 * TILEB;
    const char* Vhead = Vb + (size_t)h * (NTILE * TILEB) + (size_t)ws * 32 * TILEB;

    for (int it = 0; it < 32; ++it) {
        const char* kt = Khead + (size_t)it * TILEB;
        const char* vt = Vhead + (size_t)it * TILEB;
        // coalesced fragment loads straight into MFMA operand regs
        bf16x8 kf[8], vf[8];
        #pragma unroll
        for (int i = 0; i < 8; ++i) kf[i] = *(const bf16x8*)(kt + i * 1024 + l * 16);
        #pragma unroll
        for (int i = 0; i < 8; ++i) vf[i] = *(const bf16x8*)(vt + i * 1024 + l * 16);

        // ---- QK^T (swapped): col=q=lq, row=key = s*32 + (r&3)+8(r>>2)+4hi ----
        f32x16 sc0, sc1;
        #pragma unroll
        for (int i = 0; i < 16; ++i) { sc0[i] = 0.f; sc1[i] = 0.f; }
        #pragma unroll
        for (int kc = 0; kc < 4; ++kc) {
            sc0 = __builtin_amdgcn_mfma_f32_32x32x16_bf16(kf[kc * 2 + 0], qf[kc], sc0, 0, 0, 0);
            sc1 = __builtin_amdgcn_mfma_f32_32x32x16_bf16(kf[kc * 2 + 1], qf[kc], sc1, 0, 0, 0);
        }

        // ---- online softmax (base-2), defer-max ----
        float tm = sc0[0];
        #pragma unroll
        for (int i = 1; i < 16; ++i) tm = fmaxf(tm, sc0[i]);
        #pragma unroll
        for (int i = 0; i < 16; ++i) tm = fmaxf(tm, sc1[i]);
        tm = fmaxf(tm, __shfl_xor(tm, 32));
        if (!__all(tm <= mrun + DEFER_THR)) {
            const float nm = fmaxf(mrun, tm);
            const float alpha = EXP2F(mrun - nm);
            mrun = nm;
            lrun *= alpha;
            #pragma unroll
            for (int i = 0; i < 16; ++i) { ot0[i] *= alpha; ot1[i] *= alpha; }
        }
        float ps = 0.f;
        #pragma unroll
        for (int i = 0; i < 16; ++i) { float p = EXP2F(sc0[i] - mrun); sc0[i] = p; ps += p; }
        #pragma unroll
        for (int i = 0; i < 16; ++i) { float p = EXP2F(sc1[i] - mrun); sc1[i] = p; ps += p; }
        ps += __shfl_xor(ps, 32);
        lrun += ps;

        // ---- P -> bf16 words ----
        uint32_t pk[2][8];
        #pragma unroll
        for (int m = 0; m < 8; ++m) {
            pk[0][m] = pack_bf16(sc0[2 * m], sc0[2 * m + 1]);
            pk[1][m] = pack_bf16(sc1[2 * m], sc1[2 * m + 1]);
        }

        // ---- PV (swapped): B-frag relayout via partner exchange (l^32) ----
        #pragma unroll
        for (int c = 0; c < 4; ++c) {
            const int s = c >> 1;
            const int mb = (c & 1) * 4;
            uint32_t p0 = pk[s][mb + 0], p1 = pk[s][mb + 1];
            uint32_t p2 = pk[s][mb + 2], p3 = pk[s][mb + 3];
            uint32_t q0 = __shfl_xor(p0, 32), q1 = __shfl_xor(p1, 32);
            uint32_t q2 = __shfl_xor(p2, 32), q3 = __shfl_xor(p3, 32);
            union { uint32_t w4[4]; bf16x8 v; } pb;
            pb.w4[0] = hi ? q2 : p0;
            pb.w4[1] = hi ? q3 : p1;
            pb.w4[2] = hi ? p2 : q0;
            pb.w4[3] = hi ? p3 : q1;
            ot0 = __builtin_amdgcn_mfma_f32_32x32x16_bf16(vf[c * 2 + 0], pb.v, ot0, 0, 0, 0);
            ot1 = __builtin_amdgcn_mfma_f32_32x32x16_bf16(vf[c * 2 + 1], pb.v, ot1, 0, 0, 0);
        }
    }

    // ---- combine the two KV-splits per q-group ----
    if (ws == 1) {
        float* pp = part + (qg * 64 + l) * 34;
        #pragma unroll
        for (int r = 0; r < 16; ++r) { pp[r] = ot0[r]; pp[16 + r] = ot1[r]; }
        pp[32] = mrun; pp[33] = lrun;
    }
    __syncthreads();
    if (ws == 0) {
        const float* pp = part + (qg * 64 + l) * 34;
        const float mB = pp[32], lB = pp[33];
        const float m  = fmaxf(mrun, mB);
        const float eA = EXP2F(mrun - m), eB = EXP2F(mB - m);
        const float inv = 1.f / (lrun * eA + lB * eB);
        char* ob = obuf + qg * 8192;
        const int x = (lq & 7) << 4;
        #pragma unroll
        for (int r = 0; r < 16; ++r) {
            const int d0 = (r & 3) + 8 * (r >> 2) + 4 * hi;
            const float o0 = (ot0[r] * eA + pp[r] * eB) * inv;
            const float o1 = (ot1[r] * eA + pp[16 + r] * eB) * inv;
            *(float*)(ob + ((lq * 256 + d0 * 4) ^ x))        = o0;
            *(float*)(ob + ((lq * 256 + (32 + d0) * 4) ^ x)) = o1;
        }
    }
    __syncthreads();
    // ---- coalesced store: 64 rows x 256B ----
    {
        const int row = t >> 2, quarter = t & 3;
        const int qloc = row & 31;
        const int x = (qloc & 7) << 4;
        const char* ob = obuf + (row >> 5) * 8192;
        float* op = Og + (size_t)(qc * 64 + row) * HID + h * 64 + quarter * 16;
        #pragma unroll
        for (int i = 0; i < 4; ++i) {
            float4 v = *(const float4*)(ob + ((qloc * 256 + quarter * 64 + i * 16) ^ x));
            *(float4*)(op + i * 4) = v;
        }
    }
}

extern "C" void kernel_launch(void* const* d_in, const int* in_sizes, int n_in,
                              void* d_out, int out_size, void* d_ws, size_t ws_size,
                              hipStream_t stream) {
    const float* Q = (const float*)d_in[0];
    const float* K = (const float*)d_in[1];
    const float* V = (const float*)d_in[2];
    float* O = (float*)d_out;
    char* Kb = (char*)d_ws;                                   // 8 MB
    char* Vb = (char*)d_ws + (size_t)NHEAD * NTILE * TILEB;   // 8 MB
    dim3 pgrid(NTILE, NHEAD);
    prepack_kernel<<<pgrid, 256, 0, stream>>>(K, V, Kb, Vb);
    fattn_kernel<<<1024, 256, 0, stream>>>(Q, Kb, Vb, O);
}